// Round 11
// baseline (158.527 us; speedup 1.0000x reference)
//
#include <hip/hip_runtime.h>
#include <hip/hip_bf16.h>
#include <math.h>

typedef __attribute__((ext_vector_type(8))) short bf16x8;
typedef __attribute__((ext_vector_type(4))) short bf16x4;
typedef __attribute__((ext_vector_type(4))) float f32x4;

// async global->LDS, 16B per lane. LDS dest = wave-uniform base + lane*16.
static __device__ __forceinline__ void gld16(const void* g, void* l) {
    __builtin_amdgcn_global_load_lds(
        (const __attribute__((address_space(1))) unsigned int*)g,
        (__attribute__((address_space(3))) unsigned int*)l, 16, 0, 0);
}

static __device__ __forceinline__ short f2bf_s(float f) {
    __hip_bfloat16 h = __float2bfloat16(f);
    short s;
    __builtin_memcpy(&s, &h, 2);
    return s;
}

// ---------------------------------------------------------------------------
// Kernel 1: merged PE+LayerNorm (blocks 0..4095) and W transpose+cast
// (blocks 4096..7167). Independent work, block-uniform branch.
// ---------------------------------------------------------------------------
__global__ __launch_bounds__(256) void peln_wt_kernel(
    const float* __restrict__ emb,
    const float* __restrict__ gamma,
    const float* __restrict__ beta,
    const float* __restrict__ Wq,
    const float* __restrict__ Wk,
    const float* __restrict__ Wv,
    __hip_bfloat16* __restrict__ x,
    __hip_bfloat16* __restrict__ Wt)
{
    const int tid = threadIdx.x;
    if (blockIdx.x < 4096) {
        const int row = blockIdx.x;
        const int t   = row & 1023;
        float4 e = ((const float4*)(emb + (size_t)row * 1024))[tid];
        float v[4] = {e.x, e.y, e.z, e.w};
        float s = 0.f, ss = 0.f;
        #pragma unroll
        for (int kk = 0; kk < 4; ++kk) {
            int c = tid * 4 + kk;
            float ang = (float)t * exp2f(-13.287712379549449f * (float)(c >> 1) * (1.0f / 512.0f));
            float pe  = (c & 1) ? __cosf(ang) : __sinf(ang);
            v[kk] += pe;
            s  += v[kk];
            ss += v[kk] * v[kk];
        }
        #pragma unroll
        for (int off = 1; off < 64; off <<= 1) {
            s  += __shfl_xor(s, off);
            ss += __shfl_xor(ss, off);
        }
        __shared__ float red_s[4], red_ss[4];
        int wave = tid >> 6, lane = tid & 63;
        if (lane == 0) { red_s[wave] = s; red_ss[wave] = ss; }
        __syncthreads();
        float S  = red_s[0] + red_s[1] + red_s[2] + red_s[3];
        float SS = red_ss[0] + red_ss[1] + red_ss[2] + red_ss[3];
        float mu   = S * (1.0f / 1024.0f);
        float var  = SS * (1.0f / 1024.0f) - mu * mu;
        float rstd = rsqrtf(var + 1e-5f);
        #pragma unroll
        for (int kk = 0; kk < 4; ++kk) {
            int c = tid * 4 + kk;
            float y = (v[kk] - mu) * rstd * gamma[c] + beta[c];
            x[(size_t)row * 1024 + c] = __float2bfloat16(y);
        }
    } else {
        __shared__ __hip_bfloat16 tile[32][33];
        int wid = blockIdx.x - 4096;         // 0..3071
        int zz  = wid >> 10;
        int rem = wid & 1023;
        int bx = rem & 31, by = rem >> 5;
        int tx = tid & 31, ty = tid >> 5;    // (32,8)
        const float* src = (zz == 0) ? Wq : (zz == 1) ? Wk : Wv;
        __hip_bfloat16* dst = Wt + (size_t)zz * 1024 * 1024;
        int x0 = bx * 32, y0 = by * 32;
        #pragma unroll
        for (int kk = 0; kk < 4; ++kk)
            tile[ty + 8 * kk][tx] =
                __float2bfloat16(src[(size_t)(y0 + ty + 8 * kk) * 1024 + x0 + tx]);
        __syncthreads();
        #pragma unroll
        for (int kk = 0; kk < 4; ++kk)
            dst[(size_t)(x0 + ty + 8 * kk) * 1024 + y0 + tx] = tile[tx][ty + 8 * kk];
    }
}

// ---------------------------------------------------------------------------
// Kernel 2: fused QKV GEMM. m97 loop (BK=64, XOR-swizzled LDS), coalesced
// LDS-bounce epilogue; t==2 (V) bounce transposed straight into vt.
// ---------------------------------------------------------------------------
__global__ __launch_bounds__(256) void qkv_gemm(
    const __hip_bfloat16* __restrict__ X,    // [4096,1024] bf16
    const __hip_bfloat16* __restrict__ Wt,   // [3][1024][1024] bf16 N-major
    const float* __restrict__ bq,
    const float* __restrict__ bk,
    const float* __restrict__ bv,
    __hip_bfloat16* __restrict__ qkv,        // [2][4096][1024] bf16 (q,k)
    __hip_bfloat16* __restrict__ vt)         // [64][64][1024] bf16
{
    union SMem {
        struct { __hip_bfloat16 A[128 * 64]; __hip_bfloat16 B[128 * 64]; } s;
        __hip_bfloat16 C[128 * 132];         // epilogue bounce (pad 132)
    };
    __shared__ __align__(16) SMem sm;

    const int id   = blockIdx.x;             // 0..767
    const int xcd  = id & 7;
    const int rest = id >> 3;                // 0..95
    const int j    = rest % 3;
    const int mblk = rest / 3;               // 0..31
    const int m0   = mblk * 128;
    const int n0   = (xcd * 3 + j) * 128;    // 0..2944
    const int t    = n0 >> 10;
    const int nn0  = n0 & 1023;
    const __hip_bfloat16* W = Wt + (size_t)t * 1024 * 1024;

    const int tid  = threadIdx.x;
    const int wave = tid >> 6, lane = tid & 63;
    const int wm = wave & 1, wn = wave >> 1;
    const int lm = lane & 15, quad = lane >> 4;

    const int srow = lane >> 3;                        // 0..7
    const int skc  = ((lane & 7) ^ srow) * 8;          // element offset
    const int rbase = wave * 32;                       // rows this wave stages
    const __hip_bfloat16* gA = X + (size_t)(m0 + rbase + srow) * 1024 + skc;
    const __hip_bfloat16* gB = W + (size_t)(nn0 + rbase + srow) * 1024 + skc;
    __hip_bfloat16* lA = sm.s.A + rbase * 64;
    __hip_bfloat16* lB = sm.s.B + rbase * 64;

    f32x4 acc[4][4];
    #pragma unroll
    for (int i = 0; i < 4; ++i)
        #pragma unroll
        for (int jj = 0; jj < 4; ++jj)
            acc[i][jj] = (f32x4){0.f, 0.f, 0.f, 0.f};

    for (int k0 = 0; k0 < 1024; k0 += 64) {
        #pragma unroll
        for (int n = 0; n < 4; ++n) {
            gld16(gA + (size_t)n * 8 * 1024 + k0, lA + n * 8 * 64);
            gld16(gB + (size_t)n * 8 * 1024 + k0, lB + n * 8 * 64);
        }
        __syncthreads();

        bf16x8 a[2][4], b[2][4];
        #pragma unroll
        for (int ks = 0; ks < 2; ++ks) {
            #pragma unroll
            for (int i = 0; i < 4; ++i) {
                int row = wm * 64 + i * 16 + lm;
                a[ks][i] = *(const bf16x8*)(sm.s.A + (size_t)row * 64
                                            + (((ks * 4 + quad) ^ (lm & 7)) * 8));
            }
            #pragma unroll
            for (int jj = 0; jj < 4; ++jj) {
                int row = wn * 64 + jj * 16 + lm;
                b[ks][jj] = *(const bf16x8*)(sm.s.B + (size_t)row * 64
                                             + (((ks * 4 + quad) ^ (lm & 7)) * 8));
            }
        }
        __syncthreads();

        #pragma unroll
        for (int ks = 0; ks < 2; ++ks)
            #pragma unroll
            for (int i = 0; i < 4; ++i)
                #pragma unroll
                for (int jj = 0; jj < 4; ++jj)
                    acc[i][jj] = __builtin_amdgcn_mfma_f32_16x16x32_bf16(a[ks][i], b[ks][jj], acc[i][jj], 0, 0, 0);
    }

    const float* bias = (t == 0) ? bq : (t == 1) ? bk : bv;
    if (t < 2) {
        #pragma unroll
        for (int jj = 0; jj < 4; ++jj) {
            int col = wn * 64 + jj * 16 + lm;
            float bb = bias[nn0 + col];
            #pragma unroll
            for (int i = 0; i < 4; ++i)
                #pragma unroll
                for (int r = 0; r < 4; ++r) {
                    int row = wm * 64 + i * 16 + quad * 4 + r;
                    sm.C[(size_t)row * 132 + col] = __float2bfloat16(acc[i][jj][r] + bb);
                }
        }
        __syncthreads();
        __hip_bfloat16* out = qkv + (size_t)t * 4096 * 1024;
        #pragma unroll
        for (int c = 0; c < 8; ++c) {
            int g = tid + 256 * c;               // 0..2047 chunks of 16B
            int row = g >> 4;
            int colc = (g & 15) * 8;
            bf16x8 vch = *(const bf16x8*)&sm.C[(size_t)row * 132 + colc];
            *(bf16x8*)(out + (size_t)(m0 + row) * 1024 + nn0 + colc) = vch;
        }
    } else {
        #pragma unroll
        for (int jj = 0; jj < 4; ++jj) {
            int col = wn * 64 + jj * 16 + lm;
            float bb = bias[nn0 + col];
            #pragma unroll
            for (int i = 0; i < 4; ++i)
                #pragma unroll
                for (int r = 0; r < 4; ++r) {
                    int row = wm * 64 + i * 16 + quad * 4 + r;
                    sm.C[(size_t)col * 132 + row] = __float2bfloat16(acc[i][jj][r] + bb);
                }
        }
        __syncthreads();
        const int bbase = (m0 >> 10) * 16 + (nn0 >> 6);
        const int mloc  = m0 & 1023;
        #pragma unroll
        for (int c = 0; c < 8; ++c) {
            int g = tid + 256 * c;               // 0..2047
            int col = g >> 4;                    // 0..127
            int rch = (g & 15) * 8;              // token chunk
            bf16x8 vch = *(const bf16x8*)&sm.C[(size_t)col * 132 + rch];
            int bh = bbase + (col >> 6);
            int d  = col & 63;
            *(bf16x8*)(vt + ((size_t)bh * 64 + d) * 1024 + mloc + rch) = vch;
        }
    }
}

// ---------------------------------------------------------------------------
// Kernel 3: flash attention v9 — occupancy via LDS diet: 64-key tiles
// (Kbuf 8K + Vbuf 8K + P 16.9K = 32.9 KB -> 4 blocks/CU), VGPR<=128 via
// strict phase-split transients under __launch_bounds__(256,4).
// ---------------------------------------------------------------------------
__global__ __launch_bounds__(256, 4) void attn_kernel(
    const __hip_bfloat16* __restrict__ q,    // [4096,1024]
    const __hip_bfloat16* __restrict__ k,    // [4096,1024]
    const __hip_bfloat16* __restrict__ vt,   // [64][64][1024]
    float* __restrict__ out)                 // [4096,1024] f32
{
    __shared__ __align__(16) __hip_bfloat16 Kbuf[64 * 64];   // 8 KB [key][d]
    __shared__ __align__(16) __hip_bfloat16 Vbuf[64 * 64];   // 8 KB [d][key]
    __shared__ short ldsPT[4][32][66];                        // 16,896 B
    const int id   = blockIdx.x;             // 0..511
    const int bh   = (id & 7) * 8 + ((id >> 3) & 7);  // XCD-local K/V
    const int qblk = id >> 6;                // 0..7
    const int b = bh >> 4, h = bh & 15;
    const int wave = threadIdx.x >> 6, lane = threadIdx.x & 63;
    const int lm = lane & 15, quad = lane >> 4;
    const int qbase = qblk * 128 + wave * 32;
    const float CEXP = 0.18033688011112042f; // (1/8) * log2(e)

    // Q as B-operand frags (col n = q = lm, k = d) — loaded once
    bf16x8 bqf[2][2];
    #pragma unroll
    for (int i = 0; i < 2; ++i)
        #pragma unroll
        for (int ks = 0; ks < 2; ++ks)
            bqf[i][ks] = *(const bf16x8*)(q + (size_t)(b * 1024 + qbase + 16 * i + lm) * 1024
                                            + h * 64 + ks * 32 + quad * 8);

    const __hip_bfloat16* kg = k + (size_t)(b * 1024) * 1024 + h * 64;   // [key][d]
    const __hip_bfloat16* vg = vt + (size_t)bh * 64 * 1024;              // [d][key]
    const int srow = lane >> 3;                  // 0..7
    const int skc  = ((lane & 7) ^ srow) * 8;    // swizzled source chunk

    f32x4 OT[4][2];        // [nt = d-tile][i = q-tile]; rows = d, cols = q
    float li[2] = {0.f, 0.f};
    #pragma unroll
    for (int nt = 0; nt < 4; ++nt)
        #pragma unroll
        for (int i = 0; i < 2; ++i)
            OT[nt][i] = (f32x4){0.f, 0.f, 0.f, 0.f};

    for (int kt = 0; kt < 1024; kt += 64) {
        // ---- stage K [64 keys][64 d], V [64 d][64 keys]: 4 gld16/wave ----
        {
            int r0 = wave * 16;
            gld16(kg + (size_t)(kt + r0 + srow) * 1024 + skc, Kbuf + r0 * 64);
            gld16(kg + (size_t)(kt + r0 + 8 + srow) * 1024 + skc, Kbuf + (r0 + 8) * 64);
            gld16(vg + (size_t)(r0 + srow) * 1024 + kt + skc, Vbuf + r0 * 64);
            gld16(vg + (size_t)(r0 + 8 + srow) * 1024 + kt + skc, Vbuf + (r0 + 8) * 64);
        }
        __syncthreads();

        // ---- S^T = K·Q^T (ak transient per ks) ----
        f32x4 ST[2][4];
        #pragma unroll
        for (int i = 0; i < 2; ++i)
            #pragma unroll
            for (int jt = 0; jt < 4; ++jt)
                ST[i][jt] = (f32x4){0.f, 0.f, 0.f, 0.f};
        #pragma unroll
        for (int ks = 0; ks < 2; ++ks) {
            bf16x8 ak[4];
            #pragma unroll
            for (int jt = 0; jt < 4; ++jt)
                ak[jt] = *(const bf16x8*)(Kbuf + (size_t)(16 * jt + lm) * 64
                                          + (((ks * 4 + quad) ^ (lm & 7)) * 8));
            #pragma unroll
            for (int i = 0; i < 2; ++i)
                #pragma unroll
                for (int jt = 0; jt < 4; ++jt)
                    ST[i][jt] = __builtin_amdgcn_mfma_f32_16x16x32_bf16(ak[jt], bqf[i][ks], ST[i][jt], 0, 0, 0);
        }

        // ---- P = exp2(S*CEXP) -> wave-private LDS (b64 writes); ST dies ----
        #pragma unroll
        for (int i = 0; i < 2; ++i)
            #pragma unroll
            for (int jt = 0; jt < 4; ++jt) {
                bf16x4 pk;
                #pragma unroll
                for (int r = 0; r < 4; ++r) {
                    float p = __builtin_amdgcn_exp2f(ST[i][jt][r] * CEXP);
                    li[i] += p;
                    pk[r] = f2bf_s(p);
                }
                *(bf16x4*)&ldsPT[wave][16 * i + lm][16 * jt + quad * 4] = pk;
            }

        // ---- O^T += V^T·P^T (av/bp transient per ks; in-wave DS order) ----
        #pragma unroll
        for (int ks = 0; ks < 2; ++ks) {
            bf16x8 bp[2], av[4];
            #pragma unroll
            for (int i = 0; i < 2; ++i)
                bp[i] = *(const bf16x8*)&ldsPT[wave][16 * i + lm][ks * 32 + quad * 8];
            #pragma unroll
            for (int nt = 0; nt < 4; ++nt)
                av[nt] = *(const bf16x8*)(Vbuf + (size_t)(16 * nt + lm) * 64
                                          + (((ks * 4 + quad) ^ (lm & 7)) * 8));
            #pragma unroll
            for (int nt = 0; nt < 4; ++nt)
                #pragma unroll
                for (int i = 0; i < 2; ++i)
                    OT[nt][i] = __builtin_amdgcn_mfma_f32_16x16x32_bf16(av[nt], bp[i], OT[nt][i], 0, 0, 0);
        }
        __syncthreads();   // all K/V LDS reads done; next stage may overwrite
    }

    // li per-lane partial (q = lm): reduce across the 4 quads
    #pragma unroll
    for (int i = 0; i < 2; ++i) {
        li[i] += __shfl_xor(li[i], 16);
        li[i] += __shfl_xor(li[i], 32);
    }

    #pragma unroll
    for (int i = 0; i < 2; ++i) {
        float inv = 1.0f / li[i];
        int qrow = qbase + 16 * i + lm;
        #pragma unroll
        for (int nt = 0; nt < 4; ++nt) {
            float4 o4 = {OT[nt][i][0] * inv, OT[nt][i][1] * inv,
                         OT[nt][i][2] * inv, OT[nt][i][3] * inv};
            *(float4*)(out + (size_t)(b * 1024 + qrow) * 1024 + h * 64 + 16 * nt + quad * 4) = o4;
        }
    }
}

// ---------------------------------------------------------------------------
extern "C" void kernel_launch(void* const* d_in, const int* in_sizes, int n_in,
                              void* d_out, int out_size, void* d_ws, size_t ws_size,
                              hipStream_t stream)
{
    const float* emb   = (const float*)d_in[0];
    const float* gamma = (const float*)d_in[1];
    const float* beta  = (const float*)d_in[2];
    const float* Wq    = (const float*)d_in[3];
    const float* bq    = (const float*)d_in[4];
    const float* Wk    = (const float*)d_in[5];
    const float* bk    = (const float*)d_in[6];
    const float* Wv    = (const float*)d_in[7];
    const float* bv    = (const float*)d_in[8];
    float* out = (float*)d_out;

    __hip_bfloat16* ws  = (__hip_bfloat16*)d_ws;
    __hip_bfloat16* x   = ws;                            //  4M elems bf16
    __hip_bfloat16* Wt  = x   + (size_t)4096 * 1024;     //  3M elems
    __hip_bfloat16* qkv = Wt  + (size_t)3 * 1024 * 1024; //  8M elems (q,k)
    __hip_bfloat16* vt  = qkv + (size_t)2 * 4096 * 1024; //  4M elems (38MB)

    peln_wt_kernel<<<4096 + 3072, 256, 0, stream>>>(emb, gamma, beta, Wq, Wk, Wv, x, Wt);
    qkv_gemm<<<768, 256, 0, stream>>>(x, Wt, bq, bk, bv, qkv, vt);
    attn_kernel<<<512, 256, 0, stream>>>(qkv, qkv + (size_t)4096 * 1024, vt, out);
}

// Round 12
// 150.633 us; speedup vs baseline: 1.0524x; 1.0524x over previous
//
#include <hip/hip_runtime.h>
#include <hip/hip_bf16.h>
#include <math.h>

typedef __attribute__((ext_vector_type(8))) short bf16x8;
typedef __attribute__((ext_vector_type(4))) short bf16x4;
typedef __attribute__((ext_vector_type(4))) float f32x4;

// async global->LDS, 16B per lane. LDS dest = wave-uniform base + lane*16.
static __device__ __forceinline__ void gld16(const void* g, void* l) {
    __builtin_amdgcn_global_load_lds(
        (const __attribute__((address_space(1))) unsigned int*)g,
        (__attribute__((address_space(3))) unsigned int*)l, 16, 0, 0);
}

static __device__ __forceinline__ short f2bf_s(float f) {
    __hip_bfloat16 h = __float2bfloat16(f);
    short s;
    __builtin_memcpy(&s, &h, 2);
    return s;
}

// ---------------------------------------------------------------------------
// Kernel 1: merged PE+LayerNorm (blocks 0..4095) and W transpose+cast
// (blocks 4096..7167). Independent work, block-uniform branch.
// ---------------------------------------------------------------------------
__global__ __launch_bounds__(256) void peln_wt_kernel(
    const float* __restrict__ emb,
    const float* __restrict__ gamma,
    const float* __restrict__ beta,
    const float* __restrict__ Wq,
    const float* __restrict__ Wk,
    const float* __restrict__ Wv,
    __hip_bfloat16* __restrict__ x,
    __hip_bfloat16* __restrict__ Wt)
{
    const int tid = threadIdx.x;
    if (blockIdx.x < 4096) {
        const int row = blockIdx.x;
        const int t   = row & 1023;
        float4 e = ((const float4*)(emb + (size_t)row * 1024))[tid];
        float v[4] = {e.x, e.y, e.z, e.w};
        float s = 0.f, ss = 0.f;
        #pragma unroll
        for (int kk = 0; kk < 4; ++kk) {
            int c = tid * 4 + kk;
            float ang = (float)t * exp2f(-13.287712379549449f * (float)(c >> 1) * (1.0f / 512.0f));
            float pe  = (c & 1) ? __cosf(ang) : __sinf(ang);
            v[kk] += pe;
            s  += v[kk];
            ss += v[kk] * v[kk];
        }
        #pragma unroll
        for (int off = 1; off < 64; off <<= 1) {
            s  += __shfl_xor(s, off);
            ss += __shfl_xor(ss, off);
        }
        __shared__ float red_s[4], red_ss[4];
        int wave = tid >> 6, lane = tid & 63;
        if (lane == 0) { red_s[wave] = s; red_ss[wave] = ss; }
        __syncthreads();
        float S  = red_s[0] + red_s[1] + red_s[2] + red_s[3];
        float SS = red_ss[0] + red_ss[1] + red_ss[2] + red_ss[3];
        float mu   = S * (1.0f / 1024.0f);
        float var  = SS * (1.0f / 1024.0f) - mu * mu;
        float rstd = rsqrtf(var + 1e-5f);
        #pragma unroll
        for (int kk = 0; kk < 4; ++kk) {
            int c = tid * 4 + kk;
            float y = (v[kk] - mu) * rstd * gamma[c] + beta[c];
            x[(size_t)row * 1024 + c] = __float2bfloat16(y);
        }
    } else {
        __shared__ __hip_bfloat16 tile[32][33];
        int wid = blockIdx.x - 4096;         // 0..3071
        int zz  = wid >> 10;
        int rem = wid & 1023;
        int bx = rem & 31, by = rem >> 5;
        int tx = tid & 31, ty = tid >> 5;    // (32,8)
        const float* src = (zz == 0) ? Wq : (zz == 1) ? Wk : Wv;
        __hip_bfloat16* dst = Wt + (size_t)zz * 1024 * 1024;
        int x0 = bx * 32, y0 = by * 32;
        #pragma unroll
        for (int kk = 0; kk < 4; ++kk)
            tile[ty + 8 * kk][tx] =
                __float2bfloat16(src[(size_t)(y0 + ty + 8 * kk) * 1024 + x0 + tx]);
        __syncthreads();
        #pragma unroll
        for (int kk = 0; kk < 4; ++kk)
            dst[(size_t)(x0 + ty + 8 * kk) * 1024 + y0 + tx] = tile[tx][ty + 8 * kk];
    }
}

// ---------------------------------------------------------------------------
// Kernel 2: fused QKV GEMM. m97 loop (BK=64, XOR-swizzled LDS) with ROTATED
// pipeline: stage(n+1) issued after barrier-2, before MFMA(n) — the MFMA
// block shadows the staging latency. Coalesced LDS-bounce epilogue;
// t==2 (V) bounce transposed straight into vt.
// ---------------------------------------------------------------------------
__global__ __launch_bounds__(256) void qkv_gemm(
    const __hip_bfloat16* __restrict__ X,    // [4096,1024] bf16
    const __hip_bfloat16* __restrict__ Wt,   // [3][1024][1024] bf16 N-major
    const float* __restrict__ bq,
    const float* __restrict__ bk,
    const float* __restrict__ bv,
    __hip_bfloat16* __restrict__ qkv,        // [2][4096][1024] bf16 (q,k)
    __hip_bfloat16* __restrict__ vt)         // [64][64][1024] bf16
{
    union SMem {
        struct { __hip_bfloat16 A[128 * 64]; __hip_bfloat16 B[128 * 64]; } s;
        __hip_bfloat16 C[128 * 132];         // epilogue bounce (pad 132)
    };
    __shared__ __align__(16) SMem sm;

    const int id   = blockIdx.x;             // 0..767
    const int xcd  = id & 7;
    const int rest = id >> 3;                // 0..95
    const int j    = rest % 3;
    const int mblk = rest / 3;               // 0..31
    const int m0   = mblk * 128;
    const int n0   = (xcd * 3 + j) * 128;    // 0..2944
    const int t    = n0 >> 10;
    const int nn0  = n0 & 1023;
    const __hip_bfloat16* W = Wt + (size_t)t * 1024 * 1024;

    const int tid  = threadIdx.x;
    const int wave = tid >> 6, lane = tid & 63;
    const int wm = wave & 1, wn = wave >> 1;
    const int lm = lane & 15, quad = lane >> 4;

    const int srow = lane >> 3;                        // 0..7
    const int skc  = ((lane & 7) ^ srow) * 8;          // element offset
    const int rbase = wave * 32;                       // rows this wave stages
    const __hip_bfloat16* gA = X + (size_t)(m0 + rbase + srow) * 1024 + skc;
    const __hip_bfloat16* gB = W + (size_t)(nn0 + rbase + srow) * 1024 + skc;
    __hip_bfloat16* lA = sm.s.A + rbase * 64;
    __hip_bfloat16* lB = sm.s.B + rbase * 64;

    f32x4 acc[4][4];
    #pragma unroll
    for (int i = 0; i < 4; ++i)
        #pragma unroll
        for (int jj = 0; jj < 4; ++jj)
            acc[i][jj] = (f32x4){0.f, 0.f, 0.f, 0.f};

    // prologue: stage tile 0
    #pragma unroll
    for (int n = 0; n < 4; ++n) {
        gld16(gA + (size_t)n * 8 * 1024, lA + n * 8 * 64);
        gld16(gB + (size_t)n * 8 * 1024, lB + n * 8 * 64);
    }

    for (int k0 = 0; k0 < 1024; k0 += 64) {
        __syncthreads();                     // drains stage(k0) (vmcnt in barrier)

        bf16x8 a[2][4], b[2][4];
        #pragma unroll
        for (int ks = 0; ks < 2; ++ks) {
            #pragma unroll
            for (int i = 0; i < 4; ++i) {
                int row = wm * 64 + i * 16 + lm;
                a[ks][i] = *(const bf16x8*)(sm.s.A + (size_t)row * 64
                                            + (((ks * 4 + quad) ^ (lm & 7)) * 8));
            }
            #pragma unroll
            for (int jj = 0; jj < 4; ++jj) {
                int row = wn * 64 + jj * 16 + lm;
                b[ks][jj] = *(const bf16x8*)(sm.s.B + (size_t)row * 64
                                             + (((ks * 4 + quad) ^ (lm & 7)) * 8));
            }
        }
        __syncthreads();                     // all LDS reads done

        if (k0 + 64 < 1024) {                // stage(k0+64) under MFMA shadow
            #pragma unroll
            for (int n = 0; n < 4; ++n) {
                gld16(gA + (size_t)n * 8 * 1024 + k0 + 64, lA + n * 8 * 64);
                gld16(gB + (size_t)n * 8 * 1024 + k0 + 64, lB + n * 8 * 64);
            }
        }

        #pragma unroll
        for (int ks = 0; ks < 2; ++ks)
            #pragma unroll
            for (int i = 0; i < 4; ++i)
                #pragma unroll
                for (int jj = 0; jj < 4; ++jj)
                    acc[i][jj] = __builtin_amdgcn_mfma_f32_16x16x32_bf16(a[ks][i], b[ks][jj], acc[i][jj], 0, 0, 0);
    }

    const float* bias = (t == 0) ? bq : (t == 1) ? bk : bv;
    if (t < 2) {
        #pragma unroll
        for (int jj = 0; jj < 4; ++jj) {
            int col = wn * 64 + jj * 16 + lm;
            float bb = bias[nn0 + col];
            #pragma unroll
            for (int i = 0; i < 4; ++i)
                #pragma unroll
                for (int r = 0; r < 4; ++r) {
                    int row = wm * 64 + i * 16 + quad * 4 + r;
                    sm.C[(size_t)row * 132 + col] = __float2bfloat16(acc[i][jj][r] + bb);
                }
        }
        __syncthreads();
        __hip_bfloat16* out = qkv + (size_t)t * 4096 * 1024;
        #pragma unroll
        for (int c = 0; c < 8; ++c) {
            int g = tid + 256 * c;               // 0..2047 chunks of 16B
            int row = g >> 4;
            int colc = (g & 15) * 8;
            bf16x8 vch = *(const bf16x8*)&sm.C[(size_t)row * 132 + colc];
            *(bf16x8*)(out + (size_t)(m0 + row) * 1024 + nn0 + colc) = vch;
        }
    } else {
        #pragma unroll
        for (int jj = 0; jj < 4; ++jj) {
            int col = wn * 64 + jj * 16 + lm;
            float bb = bias[nn0 + col];
            #pragma unroll
            for (int i = 0; i < 4; ++i)
                #pragma unroll
                for (int r = 0; r < 4; ++r) {
                    int row = wm * 64 + i * 16 + quad * 4 + r;
                    sm.C[(size_t)col * 132 + row] = __float2bfloat16(acc[i][jj][r] + bb);
                }
        }
        __syncthreads();
        const int bbase = (m0 >> 10) * 16 + (nn0 >> 6);
        const int mloc  = m0 & 1023;
        #pragma unroll
        for (int c = 0; c < 8; ++c) {
            int g = tid + 256 * c;               // 0..2047
            int col = g >> 4;                    // 0..127
            int rch = (g & 15) * 8;              // token chunk
            bf16x8 vch = *(const bf16x8*)&sm.C[(size_t)col * 132 + rch];
            int bh = bbase + (col >> 6);
            int d  = col & 63;
            *(bf16x8*)(vt + ((size_t)bh * 64 + d) * 1024 + mloc + rch) = vch;
        }
    }
}

// ---------------------------------------------------------------------------
// Kernel 3: flash attention v8 (round-10 best) — LDS-staged K/V, 128-key
// tiles, 2 compute sub-rounds per stage. 128 q/block, 32 q/wave, max-free
// softmax, P^T via wave-private LDS (ds ops in-order per wave).
// ---------------------------------------------------------------------------
__global__ __launch_bounds__(256, 2) void attn_kernel(
    const __hip_bfloat16* __restrict__ q,    // [4096,1024]
    const __hip_bfloat16* __restrict__ k,    // [4096,1024]
    const __hip_bfloat16* __restrict__ vt,   // [64][64][1024]
    float* __restrict__ out)                 // [4096,1024] f32
{
    __shared__ __align__(16) __hip_bfloat16 Kbuf[128 * 64];   // 16 KB [key][d]
    __shared__ __align__(16) __hip_bfloat16 Vbuf[2][64 * 64]; // 16 KB [half][d][key]
    __shared__ short ldsPT[4][32][72];                        // 18 KB
    const int id   = blockIdx.x;             // 0..511
    const int bh   = (id & 7) * 8 + ((id >> 3) & 7);  // XCD-local K/V
    const int qblk = id >> 6;                // 0..7
    const int b = bh >> 4, h = bh & 15;
    const int wave = threadIdx.x >> 6, lane = threadIdx.x & 63;
    const int lm = lane & 15, quad = lane >> 4;
    const int qbase = qblk * 128 + wave * 32;
    const float CEXP = 0.18033688011112042f; // (1/8) * log2(e)

    bf16x8 bqf[2][2];
    #pragma unroll
    for (int i = 0; i < 2; ++i)
        #pragma unroll
        for (int ks = 0; ks < 2; ++ks)
            bqf[i][ks] = *(const bf16x8*)(q + (size_t)(b * 1024 + qbase + 16 * i + lm) * 1024
                                            + h * 64 + ks * 32 + quad * 8);

    const __hip_bfloat16* kg = k + (size_t)(b * 1024) * 1024 + h * 64;   // [key][d]
    const __hip_bfloat16* vg = vt + (size_t)bh * 64 * 1024;              // [d][key]
    const int srow = lane >> 3;                  // 0..7
    const int skc  = ((lane & 7) ^ srow) * 8;    // swizzled source chunk

    f32x4 OT[4][2];        // [nt = d-tile][i = q-tile]; rows = d, cols = q
    float li[2] = {0.f, 0.f};
    #pragma unroll
    for (int nt = 0; nt < 4; ++nt)
        #pragma unroll
        for (int i = 0; i < 2; ++i)
            OT[nt][i] = (f32x4){0.f, 0.f, 0.f, 0.f};

    for (int kt = 0; kt < 1024; kt += 128) {
        // ---- stage K [128 keys][64 d] and V [2][64 d][64 keys] ----
        #pragma unroll
        for (int n = 0; n < 4; ++n) {
            int r0 = wave * 32 + n * 8;
            gld16(kg + (size_t)(kt + r0 + srow) * 1024 + skc, Kbuf + r0 * 64);
        }
        {
            int half = wave >> 1;
            #pragma unroll
            for (int n = 0; n < 4; ++n) {
                int d0 = (wave & 1) * 32 + n * 8;
                gld16(vg + (size_t)(d0 + srow) * 1024 + kt + half * 64 + skc,
                      Vbuf[half] + d0 * 64);
            }
        }
        __syncthreads();

        #pragma unroll
        for (int sr = 0; sr < 2; ++sr) {
            bf16x8 ak[4][2], av[4][2];
            #pragma unroll
            for (int jt = 0; jt < 4; ++jt)
                #pragma unroll
                for (int ks = 0; ks < 2; ++ks)
                    ak[jt][ks] = *(const bf16x8*)(Kbuf + (size_t)(sr * 64 + 16 * jt + lm) * 64
                                                  + (((ks * 4 + quad) ^ (lm & 7)) * 8));
            #pragma unroll
            for (int nt = 0; nt < 4; ++nt)
                #pragma unroll
                for (int ks = 0; ks < 2; ++ks)
                    av[nt][ks] = *(const bf16x8*)(Vbuf[sr] + (size_t)(16 * nt + lm) * 64
                                                  + (((ks * 4 + quad) ^ (lm & 7)) * 8));
            if (sr == 1) __syncthreads();   // all tile reads done; next stage may write

            f32x4 ST[2][4];
            #pragma unroll
            for (int i = 0; i < 2; ++i)
                #pragma unroll
                for (int jt = 0; jt < 4; ++jt)
                    ST[i][jt] = (f32x4){0.f, 0.f, 0.f, 0.f};
            #pragma unroll
            for (int ks = 0; ks < 2; ++ks)
                #pragma unroll
                for (int i = 0; i < 2; ++i)
                    #pragma unroll
                    for (int jt = 0; jt < 4; ++jt)
                        ST[i][jt] = __builtin_amdgcn_mfma_f32_16x16x32_bf16(ak[jt][ks], bqf[i][ks], ST[i][jt], 0, 0, 0);

            #pragma unroll
            for (int i = 0; i < 2; ++i)
                #pragma unroll
                for (int jt = 0; jt < 4; ++jt) {
                    bf16x4 pk;
                    #pragma unroll
                    for (int r = 0; r < 4; ++r) {
                        float p = __builtin_amdgcn_exp2f(ST[i][jt][r] * CEXP);
                        li[i] += p;
                        pk[r] = f2bf_s(p);
                    }
                    *(bf16x4*)&ldsPT[wave][16 * i + lm][16 * jt + quad * 4] = pk;
                }

            bf16x8 bp[2][2];
            #pragma unroll
            for (int i = 0; i < 2; ++i)
                #pragma unroll
                for (int ks = 0; ks < 2; ++ks)
                    bp[i][ks] = *(const bf16x8*)&ldsPT[wave][16 * i + lm][ks * 32 + quad * 8];
            #pragma unroll
            for (int ks = 0; ks < 2; ++ks)
                #pragma unroll
                for (int nt = 0; nt < 4; ++nt)
                    #pragma unroll
                    for (int i = 0; i < 2; ++i)
                        OT[nt][i] = __builtin_amdgcn_mfma_f32_16x16x32_bf16(av[nt][ks], bp[i][ks], OT[nt][i], 0, 0, 0);
        }
    }

    #pragma unroll
    for (int i = 0; i < 2; ++i) {
        li[i] += __shfl_xor(li[i], 16);
        li[i] += __shfl_xor(li[i], 32);
    }

    #pragma unroll
    for (int i = 0; i < 2; ++i) {
        float inv = 1.0f / li[i];
        int qrow = qbase + 16 * i + lm;
        #pragma unroll
        for (int nt = 0; nt < 4; ++nt) {
            float4 o4 = {OT[nt][i][0] * inv, OT[nt][i][1] * inv,
                         OT[nt][i][2] * inv, OT[nt][i][3] * inv};
            *(float4*)(out + (size_t)(b * 1024 + qrow) * 1024 + h * 64 + 16 * nt + quad * 4) = o4;
        }
    }
}

// ---------------------------------------------------------------------------
extern "C" void kernel_launch(void* const* d_in, const int* in_sizes, int n_in,
                              void* d_out, int out_size, void* d_ws, size_t ws_size,
                              hipStream_t stream)
{
    const float* emb   = (const float*)d_in[0];
    const float* gamma = (const float*)d_in[1];
    const float* beta  = (const float*)d_in[2];
    const float* Wq    = (const float*)d_in[3];
    const float* bq    = (const float*)d_in[4];
    const float* Wk    = (const float*)d_in[5];
    const float* bk    = (const float*)d_in[6];
    const float* Wv    = (const float*)d_in[7];
    const float* bv    = (const float*)d_in[8];
    float* out = (float*)d_out;

    __hip_bfloat16* ws  = (__hip_bfloat16*)d_ws;
    __hip_bfloat16* x   = ws;                            //  4M elems bf16
    __hip_bfloat16* Wt  = x   + (size_t)4096 * 1024;     //  3M elems
    __hip_bfloat16* qkv = Wt  + (size_t)3 * 1024 * 1024; //  8M elems (q,k)
    __hip_bfloat16* vt  = qkv + (size_t)2 * 4096 * 1024; //  4M elems (38MB)

    peln_wt_kernel<<<4096 + 3072, 256, 0, stream>>>(emb, gamma, beta, Wq, Wk, Wv, x, Wt);
    qkv_gemm<<<768, 256, 0, stream>>>(x, Wt, bq, bk, bv, qkv, vt);
    attn_kernel<<<512, 256, 0, stream>>>(qkv, qkv + (size_t)4096 * 1024, vt, out);
}